// Round 6
// baseline (598.087 us; speedup 1.0000x reference)
//
#include <hip/hip_runtime.h>
#include <hip/hip_fp16.h>

// Hankel MPS, round 11: b-partitioned chain — no partials, no barriers.
//
// Round-10 post-mortem: barrier v3 got fused_chain to 487us, but the e-group
// grid partition forces a cross-block reduction every step: 128 MB/step of
// uncached sc1 partial reads through the MALL + grid barrier = the ~380us
// residual over the 107us MFMA floor.
//
// Round-11: partition by b ONLY. 256 blocks x 512 thr (8 waves = 4 e-quarters
// x 2 r-halves); each block owns 32 trajectories end-to-end:
//   init: v0 = enc(t=0) x H_first  (in LDS)
//   10x:  v <- sum_e enc(b,t,e) * H[e] v   (e-reduce INSIDE block via LDS)
//   final: out = v . (enc(t=11) x H_last)
// v never leaves LDS: zero partial buffers, zero sc1, zero grid sync.
// Cost shifts to H reads: 2 MB/step/block from L2 (slice fits per-XCD L2;
// whole H fits L3) ~ 5.1 GB total @ 34.5 TB/s ~ 150us, overlapping MFMA.
//
// ws: encH 25.17M | HmH 10.49M | HmL 10.49M | w1f 64K | w2f 128K  (46.3 MB)

#define B_ALL 8192
#define TT    12
#define B_T   32     // trajectories per block
#define NBLK  256    // 8192 / 32

typedef short bfrag __attribute__((ext_vector_type(8)));      // 8 bf16
typedef _Float16 hfrag __attribute__((ext_vector_type(8)));   // 8 fp16
typedef float ffrag __attribute__((ext_vector_type(16)));     // 32x32 C/D

#define O_ENC   0ULL
#define O_HMH   25165824ULL
#define O_HML   35651584ULL
#define O_W1F   46137344ULL
#define O_W2F   46202880ULL

__device__ __forceinline__ unsigned short bf16_rne(float f) {
    unsigned int u = __builtin_bit_cast(unsigned int, f);
    unsigned int r = (u + 0x7fffu + ((u >> 16) & 1u)) >> 16;
    return (unsigned short)r;
}
__device__ __forceinline__ float bf16_f32(unsigned short h) {
    unsigned int u = ((unsigned int)h) << 16;
    return __builtin_bit_cast(float, u);
}

// ---------------- prep (unchanged) ----------------
__global__ __launch_bounds__(256)
void prep_kernel(const float* __restrict__ W1, const float* __restrict__ W2,
                 const float* __restrict__ Hm,
                 __half* __restrict__ w1f, __half* __restrict__ w2f,
                 unsigned short* __restrict__ Hh, unsigned short* __restrict__ Hl)
{
    const long long N_W1 = 32768, N_W2 = 65536, N_H = 10LL * 128 * 4096;
    const long long total = N_W1 + N_W2 + N_H;
    const long long stride = (long long)gridDim.x * blockDim.x;
    for (long long idx = (long long)blockIdx.x * blockDim.x + threadIdx.x;
         idx < total; idx += stride) {
        if (idx < N_W1) {
            const int w = (int)idx;
            const int jn = w >> 11, ks = (w >> 9) & 3, half = (w >> 8) & 1;
            const int jl = (w >> 3) & 31, jj = w & 7;
            const int j = jn * 32 + jl, d = ks * 16 + half * 8 + jj;
            w1f[w] = __float2half(W1[j * 64 + d]);
        } else if (idx < N_W1 + N_W2) {
            const int w = (int)(idx - N_W1);
            const int en = w >> 14, ks2g = (w >> 9) & 31, half = (w >> 8) & 1;
            const int el = (w >> 3) & 31, jj = w & 7;
            const int e = en * 32 + el, j = ks2g * 16 + half * 8 + jj;
            w2f[w] = __float2half(W2[e * 512 + j]);
        } else {
            const long long q = idx - N_W1 - N_W2;
            const int t = (int)(q / 524288);
            const int rem = (int)(q % 524288);
            const int e = rem >> 12;
            const int f = rem & 4095;
            const int mf = f >> 11, s = (f >> 9) & 3, half = (f >> 8) & 1;
            const int l = (f >> 3) & 31, j = f & 7;
            const int p = s * 16 + half * 8 + j;
            const int r = mf * 32 + l;
            const float val = Hm[(((long long)t * 64 + p) * 128 + e) * 64 + r];
            const unsigned short hi = bf16_rne(val);
            const unsigned short lo = bf16_rne(val - bf16_f32(hi));
            Hh[q] = hi;
            Hl[q] = lo;
        }
    }
}

// ---------------- encoder (unchanged) ----------------
__global__ __launch_bounds__(256)
void enc_kernel(const float* __restrict__ x,
                const float* __restrict__ b1, const float* __restrict__ b2,
                const __half* __restrict__ w1f, const __half* __restrict__ w2f,
                __half* __restrict__ encH)
{
    __shared__ __align__(16) unsigned char smem[17408];
    float* x_s  = (float*)smem;
    __half* h_s = (__half*)smem;

    const int tid   = threadIdx.x;
    const int wv    = tid >> 6;
    const int lane  = tid & 63;
    const int l32   = lane & 31;
    const int half  = lane >> 5;
    const int msub  = wv >> 1;
    const int nhalf = wv & 1;
    const int m0    = blockIdx.x * 64;

    #pragma unroll
    for (int i = 0; i < 4; ++i) {
        const int f4 = i * 256 + tid;
        const int r = f4 >> 4, c4 = (f4 & 15) * 4;
        *(float4*)&x_s[r * 68 + c4] =
            *(const float4*)&x[(long long)(m0 + r) * 64 + c4];
    }
    __syncthreads();

    hfrag xa[4];
    #pragma unroll
    for (int ks = 0; ks < 4; ++ks) {
        const float* src = &x_s[(msub * 32 + l32) * 68 + ks * 16 + half * 8];
        const float4 a = *(const float4*)src;
        const float4 b = *(const float4*)(src + 4);
        hfrag v;
        v[0] = (_Float16)a.x; v[1] = (_Float16)a.y;
        v[2] = (_Float16)a.z; v[3] = (_Float16)a.w;
        v[4] = (_Float16)b.x; v[5] = (_Float16)b.y;
        v[6] = (_Float16)b.z; v[7] = (_Float16)b.w;
        xa[ks] = v;
    }
    __syncthreads();

    ffrag c2[2];
    c2[0] = 0.0f; c2[1] = 0.0f;

    for (int chunk = 0; chunk < 4; ++chunk) {
        ffrag c1[2];
        float b1j[2];
        #pragma unroll
        for (int nf = 0; nf < 2; ++nf) {
            const int jn = chunk * 4 + nhalf * 2 + nf;
            b1j[nf] = b1[jn * 32 + l32];
            ffrag acc = 0.0f;
            #pragma unroll
            for (int ks = 0; ks < 4; ++ks) {
                const hfrag bh = *(const hfrag*)(w1f + (jn * 4 + ks) * 512
                                                 + half * 256 + l32 * 8);
                acc = __builtin_amdgcn_mfma_f32_32x32x16_f16(xa[ks], bh, acc, 0, 0, 0);
            }
            c1[nf] = acc;
        }
        __syncthreads();
        #pragma unroll
        for (int nf = 0; nf < 2; ++nf) {
            #pragma unroll
            for (int i2 = 0; i2 < 16; ++i2) {
                const int m_row = (i2 & 3) + 8 * (i2 >> 2) + 4 * half;
                const float v = fmaxf(c1[nf][i2] + b1j[nf], 0.0f);
                h_s[(msub * 32 + m_row) * 136 + nhalf * 64 + nf * 32 + l32] =
                    __float2half(v);
            }
        }
        __syncthreads();
        #pragma unroll
        for (int ks2 = 0; ks2 < 8; ++ks2) {
            const hfrag a = *(const hfrag*)&h_s[(msub * 32 + l32) * 136
                                                + ks2 * 16 + half * 8];
            const int ks2g = chunk * 8 + ks2;
            #pragma unroll
            for (int ef = 0; ef < 2; ++ef) {
                const int en = nhalf * 2 + ef;
                const hfrag b = *(const hfrag*)(w2f + (en * 32 + ks2g) * 512
                                                + half * 256 + l32 * 8);
                c2[ef] = __builtin_amdgcn_mfma_f32_32x32x16_f16(a, b, c2[ef], 0, 0, 0);
            }
        }
    }

    #pragma unroll
    for (int ef = 0; ef < 2; ++ef) {
        const int e = nhalf * 64 + ef * 32 + l32;
        const float b2e = b2[e];
        #pragma unroll
        for (int i2 = 0; i2 < 16; ++i2) {
            const int m_row = (i2 & 3) + 8 * (i2 >> 2) + 4 * half;
            const int m_g = m0 + msub * 32 + m_row;
            encH[(long long)m_g * 128 + e] =
                __float2half(fmaxf(c2[ef][i2] + b2e, 0.0f));
        }
    }
}

// ---------------- full chain: init + 10 steps + final, all per-block ----------------
// 256 blocks x 512 thr. Block owns b0..b0+31. 8 waves: eq = wv>>1 (e-quarter,
// 32 e), rh = wv&1 (r-half). v lives in LDS vsum[64][33] across all steps.
//
// LDS map (60480 B):
//   vsum  @ 0      : [64][33] f32                  = 8448
//   enc_s @ 8448   : [128][33] f32 (one timestep)  = 16896
//   scr   @ 25344  : 6 x 32x32 f32 (eq>0 partials) = 24576   (chain)
//   hl_s  @ 25344  : [64][129] f32                 = 33024   (final, scr dead)
//   red   @ 58368  : [16][33] f32                  = 2112    (final)
__global__ __launch_bounds__(512, 2)
void chain_all(const unsigned short* __restrict__ HmH,
               const unsigned short* __restrict__ HmL,
               const __half* __restrict__ encH,
               const float* __restrict__ Hf,
               const float* __restrict__ HL,
               float* __restrict__ out)
{
    __shared__ __align__(16) unsigned char smem[60480];
    float* vsum  = (float*)smem;
    float* enc_s = (float*)(smem + 8448);
    float* scr   = (float*)(smem + 25344);
    float* hl_s  = (float*)(smem + 25344);
    float* red   = (float*)(smem + 58368);

    const int tid  = threadIdx.x;
    const int b0   = blockIdx.x * B_T;
    const int lane = tid & 63;
    const int wv   = tid >> 6;
    const int l32  = lane & 31;
    const int half = lane >> 5;
    const int eq   = wv >> 1;      // 0..3  (e-quarter)
    const int rh   = wv & 1;       // 0..1  (r-half)

    // enc staging: [128 e][32 b] f32 for one timestep (all 512 threads)
    const int sbL = tid >> 4;            // 0..31 (b-local)
    const int seo = (tid & 15) * 8;      // 0..120 (e-offset)
    #define STAGE_ENC(T)                                                      \
    {                                                                         \
        const __half* er = encH + ((size_t)(b0 + sbL) * 12 + (T)) * 128 + seo;\
        uint4 u = *(const uint4*)er;                                          \
        const __half* hp = (const __half*)&u;                                 \
        _Pragma("unroll")                                                     \
        for (int j = 0; j < 8; ++j)                                           \
            enc_s[(seo + j) * 33 + sbL] = __half2float(hp[j]);                \
    }

    // ---- init: v0[p][b] = sum_e enc(b,0,e) * Hf[e][p] ----
    {
        STAGE_ENC(0);
        __syncthreads();
        const int bI = tid & 31, pg = tid >> 5;   // pg 0..15
        const int p0 = pg * 4;
        float a0 = 0, a1 = 0, a2 = 0, a3 = 0;
        for (int e = 0; e < 128; ++e) {
            const float ev = enc_s[e * 33 + bI];
            const float4 h = *(const float4*)&Hf[e * 64 + p0];  // half-wave-uniform
            a0 += ev * h.x; a1 += ev * h.y; a2 += ev * h.z; a3 += ev * h.w;
        }
        vsum[(p0 + 0) * 33 + bI] = a0;
        vsum[(p0 + 1) * 33 + bI] = a1;
        vsum[(p0 + 2) * 33 + bI] = a2;
        vsum[(p0 + 3) * 33 + bI] = a3;
        __syncthreads();
    }

    // ---- chain: 10 steps, all in-block ----
    const unsigned short* Hsh = HmH;
    const unsigned short* Hsl = HmL;

    #pragma unroll 1
    for (int t = 1; t <= 10; ++t) {
        STAGE_ENC(t);

        // B-frags: v hi/lo split from vsum (stable since last sync)
        bfrag vbh[4], vbl[4];
        #pragma unroll
        for (int s = 0; s < 4; ++s) {
            const int p0 = s * 16 + half * 8;
            bfrag hb, lb;
            #pragma unroll
            for (int j = 0; j < 8; ++j) {
                const float f = vsum[(p0 + j) * 33 + l32];
                const unsigned short hi = bf16_rne(f);
                const unsigned short lo = bf16_rne(f - bf16_f32(hi));
                hb[j] = (short)hi;
                lb[j] = (short)lo;
            }
            vbh[s] = hb;
            vbl[s] = lb;
        }
        __syncthreads();   // enc_s staged; vsum reads complete

        // e-loop: this wave's 32-e quarter, r-half tile
        ffrag z = 0.0f;
        ffrag vn = 0.0f;
        const int e0 = eq * 32;
        #pragma unroll 2
        for (int e = e0; e < e0 + 32; ++e) {
            const float ev = enc_s[e * 33 + l32];
            const unsigned short* hbase = Hsh + (size_t)e * 4096;
            const unsigned short* lbase = Hsl + (size_t)e * 4096;
            ffrag w = z;
            #pragma unroll
            for (int s = 0; s < 4; ++s) {
                const int fo = (((rh * 4 + s) * 2 + half) * 32 + l32) * 8;
                const bfrag ah = *(const bfrag*)(hbase + fo);
                const bfrag al = *(const bfrag*)(lbase + fo);
                w = __builtin_amdgcn_mfma_f32_32x32x16_bf16(ah, vbh[s], w, 0, 0, 0);
                w = __builtin_amdgcn_mfma_f32_32x32x16_bf16(ah, vbl[s], w, 0, 0, 0);
                w = __builtin_amdgcn_mfma_f32_32x32x16_bf16(al, vbh[s], w, 0, 0, 0);
            }
            vn += w * ev;
        }
        __syncthreads();   // e-loop LDS reads done; scr region free

        // cross-eq combine in LDS: eq1..3 write, eq0 adds in ascending order
        float4* sc4 = (float4*)scr;
        if (eq != 0) {
            const int slot = (eq - 1) * 2 + rh;
            #pragma unroll
            for (int q = 0; q < 4; ++q) {
                float4 f4 = {vn[q * 4 + 0], vn[q * 4 + 1],
                             vn[q * 4 + 2], vn[q * 4 + 3]};
                sc4[(slot * 4 + q) * 64 + lane] = f4;
            }
        }
        __syncthreads();
        if (eq == 0) {
            #pragma unroll
            for (int g = 1; g < 4; ++g) {
                const int slot = (g - 1) * 2 + rh;
                #pragma unroll
                for (int q = 0; q < 4; ++q) {
                    const float4 f4 = sc4[(slot * 4 + q) * 64 + lane];
                    vn[q * 4 + 0] += f4.x; vn[q * 4 + 1] += f4.y;
                    vn[q * 4 + 2] += f4.z; vn[q * 4 + 3] += f4.w;
                }
            }
            #pragma unroll
            for (int i = 0; i < 16; ++i) {
                const int r = rh * 32 + (i & 3) + 8 * (i >> 2) + 4 * half;
                vsum[r * 33 + l32] = vn[i];
            }
        }
        __syncthreads();   // vsum ready for next step

        Hsh += 524288;
        Hsl += 524288;
    }

    // ---- final: out[b] = sum_p v[p][b] * (sum_e enc(b,11,e) * HL[p][e]) ----
    {
        STAGE_ENC(11);
        #pragma unroll
        for (int i = 0; i < 16; ++i) {
            const int idx = i * 512 + tid;       // 8192 floats of HL [p][e]
            hl_s[(idx >> 7) * 129 + (idx & 127)] = HL[idx];
        }
        __syncthreads();
        const int bI = tid & 31, pg = tid >> 5;
        const int p0 = pg * 4;
        float s = 0.0f;
        #pragma unroll
        for (int i = 0; i < 4; ++i) {
            float L = 0.0f;
            #pragma unroll 16
            for (int e = 0; e < 128; ++e)
                L += enc_s[e * 33 + bI] * hl_s[(p0 + i) * 129 + e];
            s += vsum[(p0 + i) * 33 + bI] * L;
        }
        red[pg * 33 + bI] = s;
        __syncthreads();
        if (tid < 32) {
            float acc = 0.0f;
            #pragma unroll
            for (int g = 0; g < 16; ++g)
                acc += red[g * 33 + tid];
            out[b0 + tid] = acc;
        }
    }
    #undef STAGE_ENC
}

extern "C" void kernel_launch(void* const* d_in, const int* in_sizes, int n_in,
                              void* d_out, int out_size, void* d_ws, size_t ws_size,
                              hipStream_t stream) {
    const float* x  = (const float*)d_in[0];
    const float* W1 = (const float*)d_in[1];
    const float* b1 = (const float*)d_in[2];
    const float* W2 = (const float*)d_in[3];
    const float* b2 = (const float*)d_in[4];
    const float* Hf = (const float*)d_in[5];
    const float* Hm = (const float*)d_in[6];
    const float* HL = (const float*)d_in[7];
    float* out = (float*)d_out;
    (void)in_sizes; (void)n_in; (void)out_size; (void)ws_size;

    char* ws = (char*)d_ws;
    __half* encH        = (__half*)(ws + O_ENC);
    unsigned short* HmH = (unsigned short*)(ws + O_HMH);
    unsigned short* HmL = (unsigned short*)(ws + O_HML);
    __half* w1f         = (__half*)(ws + O_W1F);
    __half* w2f         = (__half*)(ws + O_W2F);

    prep_kernel<<<dim3(5216), dim3(256), 0, stream>>>(W1, W2, Hm, w1f, w2f, HmH, HmL);
    enc_kernel<<<dim3(1536), dim3(256), 0, stream>>>(x, b1, b2, w1f, w2f, encH);
    chain_all<<<dim3(NBLK), dim3(512), 0, stream>>>(HmH, HmL, encH, Hf, HL, out);
}

// Round 7
// 402.864 us; speedup vs baseline: 1.4846x; 1.4846x over previous
//
#include <hip/hip_runtime.h>
#include <hip/hip_fp16.h>

// Hankel MPS, round 12: b-partitioned chain + pipelined H loads.
//
// Round-11 post-mortem: restructure killed all coherence traffic (WRITE 32KB)
// but chain_all stayed 485us == r10's e-loop time. VGPR_Count=60: the
// launch_bounds(512,2) cap left no registers to prefetch -> each e iter
// serializes load(8x L2, ~250cy) -> waitcnt -> 12 MFMA. Latency-bound:
// MfmaUtil 23%, VALUBusy 8.5%, HBM 2.5%.
//
// Round-12 (one lever: pipeline the loads):
//  - launch_bounds(512,1): grid is 1 block/CU already; lift the VGPR cap.
//  - explicit 1-deep e-pipeline: prefetch e+1 frags into a 2nd register set
//    before e's MFMAs (unroll 2 renames the ping-pong). Load latency hides
//    under the ~768cy the wave's MFMAs occupy on the shared matrix pipe.
//    Final prefetch reads <=8KB past the slice into adjacent ws (allocated).
//  - scr combine stride 64->66 float4: kills stride-16B 8-way bank conflict.
//
// ws: encH 25.17M | HmH 10.49M | HmL 10.49M | w1f 64K | w2f 128K  (46.3 MB)

#define B_ALL 8192
#define TT    12
#define B_T   32     // trajectories per block
#define NBLK  256    // 8192 / 32

typedef short bfrag __attribute__((ext_vector_type(8)));      // 8 bf16
typedef _Float16 hfrag __attribute__((ext_vector_type(8)));   // 8 fp16
typedef float ffrag __attribute__((ext_vector_type(16)));     // 32x32 C/D

#define O_ENC   0ULL
#define O_HMH   25165824ULL
#define O_HML   35651584ULL
#define O_W1F   46137344ULL
#define O_W2F   46202880ULL

__device__ __forceinline__ unsigned short bf16_rne(float f) {
    unsigned int u = __builtin_bit_cast(unsigned int, f);
    unsigned int r = (u + 0x7fffu + ((u >> 16) & 1u)) >> 16;
    return (unsigned short)r;
}
__device__ __forceinline__ float bf16_f32(unsigned short h) {
    unsigned int u = ((unsigned int)h) << 16;
    return __builtin_bit_cast(float, u);
}

// ---------------- prep (unchanged) ----------------
__global__ __launch_bounds__(256)
void prep_kernel(const float* __restrict__ W1, const float* __restrict__ W2,
                 const float* __restrict__ Hm,
                 __half* __restrict__ w1f, __half* __restrict__ w2f,
                 unsigned short* __restrict__ Hh, unsigned short* __restrict__ Hl)
{
    const long long N_W1 = 32768, N_W2 = 65536, N_H = 10LL * 128 * 4096;
    const long long total = N_W1 + N_W2 + N_H;
    const long long stride = (long long)gridDim.x * blockDim.x;
    for (long long idx = (long long)blockIdx.x * blockDim.x + threadIdx.x;
         idx < total; idx += stride) {
        if (idx < N_W1) {
            const int w = (int)idx;
            const int jn = w >> 11, ks = (w >> 9) & 3, half = (w >> 8) & 1;
            const int jl = (w >> 3) & 31, jj = w & 7;
            const int j = jn * 32 + jl, d = ks * 16 + half * 8 + jj;
            w1f[w] = __float2half(W1[j * 64 + d]);
        } else if (idx < N_W1 + N_W2) {
            const int w = (int)(idx - N_W1);
            const int en = w >> 14, ks2g = (w >> 9) & 31, half = (w >> 8) & 1;
            const int el = (w >> 3) & 31, jj = w & 7;
            const int e = en * 32 + el, j = ks2g * 16 + half * 8 + jj;
            w2f[w] = __float2half(W2[e * 512 + j]);
        } else {
            const long long q = idx - N_W1 - N_W2;
            const int t = (int)(q / 524288);
            const int rem = (int)(q % 524288);
            const int e = rem >> 12;
            const int f = rem & 4095;
            const int mf = f >> 11, s = (f >> 9) & 3, half = (f >> 8) & 1;
            const int l = (f >> 3) & 31, j = f & 7;
            const int p = s * 16 + half * 8 + j;
            const int r = mf * 32 + l;
            const float val = Hm[(((long long)t * 64 + p) * 128 + e) * 64 + r];
            const unsigned short hi = bf16_rne(val);
            const unsigned short lo = bf16_rne(val - bf16_f32(hi));
            Hh[q] = hi;
            Hl[q] = lo;
        }
    }
}

// ---------------- encoder (unchanged) ----------------
__global__ __launch_bounds__(256)
void enc_kernel(const float* __restrict__ x,
                const float* __restrict__ b1, const float* __restrict__ b2,
                const __half* __restrict__ w1f, const __half* __restrict__ w2f,
                __half* __restrict__ encH)
{
    __shared__ __align__(16) unsigned char smem[17408];
    float* x_s  = (float*)smem;
    __half* h_s = (__half*)smem;

    const int tid   = threadIdx.x;
    const int wv    = tid >> 6;
    const int lane  = tid & 63;
    const int l32   = lane & 31;
    const int half  = lane >> 5;
    const int msub  = wv >> 1;
    const int nhalf = wv & 1;
    const int m0    = blockIdx.x * 64;

    #pragma unroll
    for (int i = 0; i < 4; ++i) {
        const int f4 = i * 256 + tid;
        const int r = f4 >> 4, c4 = (f4 & 15) * 4;
        *(float4*)&x_s[r * 68 + c4] =
            *(const float4*)&x[(long long)(m0 + r) * 64 + c4];
    }
    __syncthreads();

    hfrag xa[4];
    #pragma unroll
    for (int ks = 0; ks < 4; ++ks) {
        const float* src = &x_s[(msub * 32 + l32) * 68 + ks * 16 + half * 8];
        const float4 a = *(const float4*)src;
        const float4 b = *(const float4*)(src + 4);
        hfrag v;
        v[0] = (_Float16)a.x; v[1] = (_Float16)a.y;
        v[2] = (_Float16)a.z; v[3] = (_Float16)a.w;
        v[4] = (_Float16)b.x; v[5] = (_Float16)b.y;
        v[6] = (_Float16)b.z; v[7] = (_Float16)b.w;
        xa[ks] = v;
    }
    __syncthreads();

    ffrag c2[2];
    c2[0] = 0.0f; c2[1] = 0.0f;

    for (int chunk = 0; chunk < 4; ++chunk) {
        ffrag c1[2];
        float b1j[2];
        #pragma unroll
        for (int nf = 0; nf < 2; ++nf) {
            const int jn = chunk * 4 + nhalf * 2 + nf;
            b1j[nf] = b1[jn * 32 + l32];
            ffrag acc = 0.0f;
            #pragma unroll
            for (int ks = 0; ks < 4; ++ks) {
                const hfrag bh = *(const hfrag*)(w1f + (jn * 4 + ks) * 512
                                                 + half * 256 + l32 * 8);
                acc = __builtin_amdgcn_mfma_f32_32x32x16_f16(xa[ks], bh, acc, 0, 0, 0);
            }
            c1[nf] = acc;
        }
        __syncthreads();
        #pragma unroll
        for (int nf = 0; nf < 2; ++nf) {
            #pragma unroll
            for (int i2 = 0; i2 < 16; ++i2) {
                const int m_row = (i2 & 3) + 8 * (i2 >> 2) + 4 * half;
                const float v = fmaxf(c1[nf][i2] + b1j[nf], 0.0f);
                h_s[(msub * 32 + m_row) * 136 + nhalf * 64 + nf * 32 + l32] =
                    __float2half(v);
            }
        }
        __syncthreads();
        #pragma unroll
        for (int ks2 = 0; ks2 < 8; ++ks2) {
            const hfrag a = *(const hfrag*)&h_s[(msub * 32 + l32) * 136
                                                + ks2 * 16 + half * 8];
            const int ks2g = chunk * 8 + ks2;
            #pragma unroll
            for (int ef = 0; ef < 2; ++ef) {
                const int en = nhalf * 2 + ef;
                const hfrag b = *(const hfrag*)(w2f + (en * 32 + ks2g) * 512
                                                + half * 256 + l32 * 8);
                c2[ef] = __builtin_amdgcn_mfma_f32_32x32x16_f16(a, b, c2[ef], 0, 0, 0);
            }
        }
    }

    #pragma unroll
    for (int ef = 0; ef < 2; ++ef) {
        const int e = nhalf * 64 + ef * 32 + l32;
        const float b2e = b2[e];
        #pragma unroll
        for (int i2 = 0; i2 < 16; ++i2) {
            const int m_row = (i2 & 3) + 8 * (i2 >> 2) + 4 * half;
            const int m_g = m0 + msub * 32 + m_row;
            encH[(long long)m_g * 128 + e] =
                __float2half(fmaxf(c2[ef][i2] + b2e, 0.0f));
        }
    }
}

// ---------------- full chain: init + 10 steps + final, all per-block ----------------
// 256 blocks x 512 thr (1 block/CU). Block owns b0..b0+31. 8 waves:
// eq = wv>>1 (e-quarter, 32 e), rh = wv&1 (r-half). v lives in LDS across
// all steps. e-loop software-pipelined: prefetch e+1 frags before e's MFMAs.
//
// LDS map (60480 B):
//   vsum  @ 0      : [64][33] f32                  = 8448
//   enc_s @ 8448   : [128][33] f32 (one timestep)  = 16896
//   scr   @ 25344  : 6x4 float4 rows, stride 66    = 25312   (chain)
//   hl_s  @ 25344  : [64][129] f32                 = 33024   (final, scr dead)
//   red   @ 58368  : [16][33] f32                  = 2112    (final)
__global__ __launch_bounds__(512, 1)
void chain_all(const unsigned short* __restrict__ HmH,
               const unsigned short* __restrict__ HmL,
               const __half* __restrict__ encH,
               const float* __restrict__ Hf,
               const float* __restrict__ HL,
               float* __restrict__ out)
{
    __shared__ __align__(16) unsigned char smem[60480];
    float* vsum  = (float*)smem;
    float* enc_s = (float*)(smem + 8448);
    float* scr   = (float*)(smem + 25344);
    float* hl_s  = (float*)(smem + 25344);
    float* red   = (float*)(smem + 58368);

    const int tid  = threadIdx.x;
    const int b0   = blockIdx.x * B_T;
    const int lane = tid & 63;
    const int wv   = tid >> 6;
    const int l32  = lane & 31;
    const int half = lane >> 5;
    const int eq   = wv >> 1;      // 0..3  (e-quarter)
    const int rh   = wv & 1;       // 0..1  (r-half)

    // enc staging: [128 e][32 b] f32 for one timestep (all 512 threads)
    const int sbL = tid >> 4;            // 0..31 (b-local)
    const int seo = (tid & 15) * 8;      // 0..120 (e-offset)
    #define STAGE_ENC(T)                                                      \
    {                                                                         \
        const __half* er = encH + ((size_t)(b0 + sbL) * 12 + (T)) * 128 + seo;\
        uint4 u = *(const uint4*)er;                                          \
        const __half* hp = (const __half*)&u;                                 \
        _Pragma("unroll")                                                     \
        for (int j = 0; j < 8; ++j)                                           \
            enc_s[(seo + j) * 33 + sbL] = __half2float(hp[j]);                \
    }

    // ---- init: v0[p][b] = sum_e enc(b,0,e) * Hf[e][p] ----
    {
        STAGE_ENC(0);
        __syncthreads();
        const int bI = tid & 31, pg = tid >> 5;   // pg 0..15
        const int p0 = pg * 4;
        float a0 = 0, a1 = 0, a2 = 0, a3 = 0;
        for (int e = 0; e < 128; ++e) {
            const float ev = enc_s[e * 33 + bI];
            const float4 h = *(const float4*)&Hf[e * 64 + p0];  // half-wave-uniform
            a0 += ev * h.x; a1 += ev * h.y; a2 += ev * h.z; a3 += ev * h.w;
        }
        vsum[(p0 + 0) * 33 + bI] = a0;
        vsum[(p0 + 1) * 33 + bI] = a1;
        vsum[(p0 + 2) * 33 + bI] = a2;
        vsum[(p0 + 3) * 33 + bI] = a3;
        __syncthreads();
    }

    // ---- chain: 10 steps, all in-block ----
    const unsigned short* Hsh = HmH;
    const unsigned short* Hsl = HmL;
    // per-lane fragment offset within an e-slice (ushorts):
    // fo(s) = rh*2048 + s*512 + half*256 + l32*8
    const int lanoff = rh * 2048 + half * 256 + l32 * 8;

    #pragma unroll 1
    for (int t = 1; t <= 10; ++t) {
        STAGE_ENC(t);

        // B-frags: v hi/lo split from vsum (stable since last sync)
        bfrag vbh[4], vbl[4];
        #pragma unroll
        for (int s = 0; s < 4; ++s) {
            const int p0 = s * 16 + half * 8;
            bfrag hb, lb;
            #pragma unroll
            for (int j = 0; j < 8; ++j) {
                const float f = vsum[(p0 + j) * 33 + l32];
                const unsigned short hi = bf16_rne(f);
                const unsigned short lo = bf16_rne(f - bf16_f32(hi));
                hb[j] = (short)hi;
                lb[j] = (short)lo;
            }
            vbh[s] = hb;
            vbl[s] = lb;
        }
        __syncthreads();   // enc_s staged; vsum reads complete

        // e-loop: this wave's 32-e quarter, software-pipelined (prefetch e+1)
        const unsigned short* hp = Hsh + (size_t)(eq * 32) * 4096 + lanoff;
        const unsigned short* lp = Hsl + (size_t)(eq * 32) * 4096 + lanoff;
        bfrag cah[4], cal[4];
        #pragma unroll
        for (int s = 0; s < 4; ++s) {
            cah[s] = *(const bfrag*)(hp + s * 512);
            cal[s] = *(const bfrag*)(lp + s * 512);
        }
        ffrag z = 0.0f;
        ffrag vn = 0.0f;
        #pragma unroll 2
        for (int e = 0; e < 32; ++e) {
            hp += 4096; lp += 4096;
            // prefetch next e (last iter reads <=8KB past slice: allocated ws)
            bfrag nah[4], nal[4];
            #pragma unroll
            for (int s = 0; s < 4; ++s) {
                nah[s] = *(const bfrag*)(hp + s * 512);
                nal[s] = *(const bfrag*)(lp + s * 512);
            }
            const float ev = enc_s[(eq * 32 + e) * 33 + l32];
            ffrag w = z;
            #pragma unroll
            for (int s = 0; s < 4; ++s) {
                w = __builtin_amdgcn_mfma_f32_32x32x16_bf16(cah[s], vbh[s], w, 0, 0, 0);
                w = __builtin_amdgcn_mfma_f32_32x32x16_bf16(cah[s], vbl[s], w, 0, 0, 0);
                w = __builtin_amdgcn_mfma_f32_32x32x16_bf16(cal[s], vbh[s], w, 0, 0, 0);
            }
            vn += w * ev;
            #pragma unroll
            for (int s = 0; s < 4; ++s) { cah[s] = nah[s]; cal[s] = nal[s]; }
        }
        __syncthreads();   // e-loop LDS reads done; scr region free

        // cross-eq combine in LDS (stride 66 float4 kills bank conflicts)
        float4* sc4 = (float4*)scr;
        if (eq != 0) {
            const int slot = (eq - 1) * 2 + rh;
            #pragma unroll
            for (int q = 0; q < 4; ++q) {
                float4 f4 = {vn[q * 4 + 0], vn[q * 4 + 1],
                             vn[q * 4 + 2], vn[q * 4 + 3]};
                sc4[(slot * 4 + q) * 66 + lane] = f4;
            }
        }
        __syncthreads();
        if (eq == 0) {
            #pragma unroll
            for (int g = 1; g < 4; ++g) {
                const int slot = (g - 1) * 2 + rh;
                #pragma unroll
                for (int q = 0; q < 4; ++q) {
                    const float4 f4 = sc4[(slot * 4 + q) * 66 + lane];
                    vn[q * 4 + 0] += f4.x; vn[q * 4 + 1] += f4.y;
                    vn[q * 4 + 2] += f4.z; vn[q * 4 + 3] += f4.w;
                }
            }
            #pragma unroll
            for (int i = 0; i < 16; ++i) {
                const int r = rh * 32 + (i & 3) + 8 * (i >> 2) + 4 * half;
                vsum[r * 33 + l32] = vn[i];
            }
        }
        __syncthreads();   // vsum ready for next step

        Hsh += 524288;
        Hsl += 524288;
    }

    // ---- final: out[b] = sum_p v[p][b] * (sum_e enc(b,11,e) * HL[p][e]) ----
    {
        STAGE_ENC(11);
        #pragma unroll
        for (int i = 0; i < 16; ++i) {
            const int idx = i * 512 + tid;       // 8192 floats of HL [p][e]
            hl_s[(idx >> 7) * 129 + (idx & 127)] = HL[idx];
        }
        __syncthreads();
        const int bI = tid & 31, pg = tid >> 5;
        const int p0 = pg * 4;
        float s = 0.0f;
        #pragma unroll
        for (int i = 0; i < 4; ++i) {
            float L = 0.0f;
            #pragma unroll 16
            for (int e = 0; e < 128; ++e)
                L += enc_s[e * 33 + bI] * hl_s[(p0 + i) * 129 + e];
            s += vsum[(p0 + i) * 33 + bI] * L;
        }
        red[pg * 33 + bI] = s;
        __syncthreads();
        if (tid < 32) {
            float acc = 0.0f;
            #pragma unroll
            for (int g = 0; g < 16; ++g)
                acc += red[g * 33 + tid];
            out[b0 + tid] = acc;
        }
    }
    #undef STAGE_ENC
}

extern "C" void kernel_launch(void* const* d_in, const int* in_sizes, int n_in,
                              void* d_out, int out_size, void* d_ws, size_t ws_size,
                              hipStream_t stream) {
    const float* x  = (const float*)d_in[0];
    const float* W1 = (const float*)d_in[1];
    const float* b1 = (const float*)d_in[2];
    const float* W2 = (const float*)d_in[3];
    const float* b2 = (const float*)d_in[4];
    const float* Hf = (const float*)d_in[5];
    const float* Hm = (const float*)d_in[6];
    const float* HL = (const float*)d_in[7];
    float* out = (float*)d_out;
    (void)in_sizes; (void)n_in; (void)out_size; (void)ws_size;

    char* ws = (char*)d_ws;
    __half* encH        = (__half*)(ws + O_ENC);
    unsigned short* HmH = (unsigned short*)(ws + O_HMH);
    unsigned short* HmL = (unsigned short*)(ws + O_HML);
    __half* w1f         = (__half*)(ws + O_W1F);
    __half* w2f         = (__half*)(ws + O_W2F);

    prep_kernel<<<dim3(5216), dim3(256), 0, stream>>>(W1, W2, Hm, w1f, w2f, HmH, HmL);
    enc_kernel<<<dim3(1536), dim3(256), 0, stream>>>(x, b1, b2, w1f, w2f, encH);
    chain_all<<<dim3(NBLK), dim3(512), 0, stream>>>(HmH, HmL, encH, Hf, HL, out);
}